// Round 8
// baseline (203.680 us; speedup 1.0000x reference)
//
#include <hip/hip_runtime.h>
#include <hip/hip_bf16.h>

// MHA: B=2, S=2048, D=1024, H=16, Dk=64. fp32 in/out, bf16 MFMA internally.

typedef __attribute__((ext_vector_type(8))) short short8;
typedef __attribute__((ext_vector_type(4))) float f32x4;
typedef __attribute__((ext_vector_type(2))) float f32x2;
typedef unsigned short u16;
typedef unsigned int u32;

static __device__ __forceinline__ u16 f2bf(float f) {
    union { float f; u32 u; } c; c.f = f;
    u32 u = c.u;
    u32 r = u + 0x7fffu + ((u >> 16) & 1u);   // RNE
    return (u16)(r >> 16);
}
static __device__ __forceinline__ float bf2f(u16 x) {
    union { u32 u; float f; } c; c.u = ((u32)x) << 16;
    return c.f;
}

#define GL1(p) ((const __attribute__((address_space(1))) void*)(p))
#define LD3(p) ((__attribute__((address_space(3))) void*)(p))
static __device__ __forceinline__ void gld16(const void* g, void* l) {
    __builtin_amdgcn_global_load_lds(GL1(g), LD3(l), 16, 0, 0);
}

// log2(e)/8 — folded into Wq/bq in prep, so Q comes out pre-scaled
#define Q_PRESCALE 0.18033688011112042f

// ---------------- prep -------------------------------------------------------
__global__ __launch_bounds__(256) void prep(
    const float* __restrict__ X, u16* __restrict__ Xb,
    const float* __restrict__ Wq, const float* __restrict__ Wk,
    const float* __restrict__ Wv, const float* __restrict__ Wo,
    const float* __restrict__ bq, const float* __restrict__ bk,
    const float* __restrict__ bv,
    u16* __restrict__ Wqkv, u16* __restrict__ Wto, float* __restrict__ Bp)
{
    int id = blockIdx.x;
    int t = threadIdx.x;
    if (id == 5120) {
        for (int i = t; i < 3072; i += 256) {
            int wsel = i >> 10, c = i & 1023;
            float v = (wsel == 0) ? bq[c] * Q_PRESCALE : (wsel == 1 ? bk[c] : bv[c]);
            Bp[i] = v;
        }
        return;
    }
    if (id >= 1024) {
        int i = (id - 1024) * 1024 + t * 4;
        float4 v = *reinterpret_cast<const float4*>(X + i);
        ushort4 o;
        o.x = f2bf(v.x); o.y = f2bf(v.y); o.z = f2bf(v.z); o.w = f2bf(v.w);
        *reinterpret_cast<ushort4*>(Xb + i) = o;
        return;
    }
    int which = id >> 8;
    const float* W; u16* T; float sc;
    switch (which) {
        case 0: W = Wq; T = Wqkv;                sc = Q_PRESCALE; break;
        case 1: W = Wk; T = Wqkv + 1024 * 1024;  sc = 1.0f; break;
        case 2: W = Wv; T = Wqkv + 2048 * 1024;  sc = 1.0f; break;
        default: W = Wo; T = Wto;                sc = 1.0f; break;
    }
    int rem = id & 255;
    int n0 = (rem & 15) * 64, k0 = (rem >> 4) * 64;
    __shared__ float tile[64][65];
    int r = t / 16, c4 = (t % 16) * 4;
    #pragma unroll
    for (int p = 0; p < 4; p++) {
        int row = p * 16 + r;
        float4 v = *reinterpret_cast<const float4*>(W + (k0 + row) * 1024 + n0 + c4);
        tile[row][c4 + 0] = v.x * sc; tile[row][c4 + 1] = v.y * sc;
        tile[row][c4 + 2] = v.z * sc; tile[row][c4 + 3] = v.w * sc;
    }
    __syncthreads();
    #pragma unroll
    for (int p = 0; p < 4; p++) {
        int nrow = p * 16 + r;
        ushort4 o;
        o.x = f2bf(tile[c4 + 0][nrow]); o.y = f2bf(tile[c4 + 1][nrow]);
        o.z = f2bf(tile[c4 + 2][nrow]); o.w = f2bf(tile[c4 + 3][nrow]);
        *reinterpret_cast<ushort4*>(T + (n0 + nrow) * 1024 + k0 + c4) = o;
    }
}

// ---------------- fused QKV GEMM, async-pipelined, XCD-swizzled --------------
// bid = col*32 + row -> bid%8 = row%8: all 24 col-blocks sharing an A row-
// stripe land on ONE XCD (per-XCD L2 working set: A 1MB + B, vs 8x A refetch).
__global__ __launch_bounds__(256, 3) void gemm_qkv(
    const u16* __restrict__ Xb, const u16* __restrict__ Wqkv,
    const float* __restrict__ Bp,
    u16* __restrict__ Qb, u16* __restrict__ Kb, u16* __restrict__ Vtg)
{
    __shared__ __align__(16) u16 As[2][128 * 32];
    __shared__ __align__(16) u16 Bs[2][128 * 32];
    int t = threadIdx.x;
    int w = t >> 6, lane = t & 63, l15 = lane & 15, quad = lane >> 4;
    int wm = (w >> 1) * 64, wn = (w & 1) * 64;
    int bid = blockIdx.x;
    int row0 = (bid & 31) * 128, col0 = (bid >> 5) * 128;

    int drow = lane >> 2;
    int gc8 = ((lane & 3) ^ (drow & 3) ^ ((drow >> 2) & 3)) * 8;
    int asw = ((quad ^ (l15 & 3) ^ ((l15 >> 2) & 3)) & 3) * 8;

    const u16* Ag = Xb + (row0 + drow) * 1024 + gc8;
    const u16* Bg = Wqkv + (col0 + drow) * 1024 + gc8;

    f32x4 acc[4][4];
    #pragma unroll
    for (int i = 0; i < 4; i++)
        #pragma unroll
        for (int j = 0; j < 4; j++)
            acc[i][j] = (f32x4){0.f, 0.f, 0.f, 0.f};

    #pragma unroll
    for (int q = 0; q < 2; q++) {
        int rr = w * 32 + q * 16;
        gld16(Ag + rr * 1024, &As[0][rr * 32]);
        gld16(Bg + rr * 1024, &Bs[0][rr * 32]);
    }
    for (int kt = 0; kt < 32; kt++) {
        __syncthreads();
        int cur = kt & 1;
        if (kt < 31) {
            int k0 = (kt + 1) * 32;
            #pragma unroll
            for (int q = 0; q < 2; q++) {
                int rr = w * 32 + q * 16;
                gld16(Ag + rr * 1024 + k0, &As[cur ^ 1][rr * 32]);
                gld16(Bg + rr * 1024 + k0, &Bs[cur ^ 1][rr * 32]);
            }
        }
        short8 a[4], b[4];
        #pragma unroll
        for (int i = 0; i < 4; i++)
            a[i] = *reinterpret_cast<const short8*>(&As[cur][(wm + i * 16 + l15) * 32 + asw]);
        #pragma unroll
        for (int j = 0; j < 4; j++)
            b[j] = *reinterpret_cast<const short8*>(&Bs[cur][(wn + j * 16 + l15) * 32 + asw]);
        #pragma unroll
        for (int i = 0; i < 4; i++)
            #pragma unroll
            for (int j = 0; j < 4; j++)
                acc[i][j] = __builtin_amdgcn_mfma_f32_16x16x32_bf16(a[i], b[j], acc[i][j], 0, 0, 0);
    }

    int osel = col0 >> 10;                 // 0=Q 1=K 2=V (block-uniform)
    if (osel == 2) {
        #pragma unroll
        for (int i = 0; i < 4; i++) {
            int gr = row0 + wm + i * 16 + quad * 4;
            int b_ = gr >> 11, s = gr & 2047;
            #pragma unroll
            for (int j = 0; j < 4; j++) {
                int col = col0 + wn + j * 16 + l15;
                int c = col & 1023, h = c >> 6, d = c & 63;
                float bb = Bp[col];
                ushort4 pk;
                pk.x = f2bf(acc[i][j][0] + bb);
                pk.y = f2bf(acc[i][j][1] + bb);
                pk.z = f2bf(acc[i][j][2] + bb);
                pk.w = f2bf(acc[i][j][3] + bb);
                *reinterpret_cast<ushort4*>(&Vtg[((b_ * 16 + h) * 64 + d) * 2048 + s]) = pk;
            }
        }
    } else {
        u16* dst = osel ? Kb : Qb;
        #pragma unroll
        for (int i = 0; i < 4; i++) {
            int rowb = row0 + wm + i * 16 + quad * 4;
            #pragma unroll
            for (int j = 0; j < 4; j++) {
                int col = col0 + wn + j * 16 + l15;
                int c = col & 1023, h = c >> 6, d = c & 63;
                float bb = Bp[col];
                #pragma unroll
                for (int r = 0; r < 4; r++) {
                    int gr = rowb + r;
                    int b_ = gr >> 11, s = gr & 2047;
                    dst[(((b_ << 4) + h) * 2048 + s) * 64 + d] = f2bf(acc[i][j][r] + bb);
                }
            }
        }
    }
}

// ---------------- Attention, full-K per block, XCD-swizzled ------------------
// v9: KVBLK=128 (two 64-kv half-tiles per iteration). 16 outer iterations
//     -> 32 barriers (r7 had 64), 2x MFMA per barrier, half the loop/addr
//     overhead. Ks/Vt staged as 2x 64x64 halves; Ps (64x64) is wave-private
//     and reused across halves within an iteration (per-wave DS ops are
//     in-order, so pack-half1 writes cannot pass PV-half0 reads).
//     LDS 40KB -> exactly 4 blocks/CU (unchanged from r7's grid limit).
//     All address formulas / per-element math identical to the r7 kernel.
__global__ __launch_bounds__(256) void attn(
    const u16* __restrict__ Qb, const u16* __restrict__ Kb,
    const u16* __restrict__ Vtg, u16* __restrict__ Ob)
{
    int bid = blockIdx.x;
    int bh = bid & 31, qt = bid >> 5;      // qt in [0,32), 64 q-rows each
    int b_ = bh >> 4, h = bh & 15;
    const u16* Qp = Qb + bh * (2048 * 64);
    const u16* Kp = Kb + bh * (2048 * 64);
    const u16* Vp = Vtg + bh * (64 * 2048);

    __shared__ __align__(16) u16 Ks[2][64 * 64];
    __shared__ __align__(16) u16 Vt[2][64 * 64];
    __shared__ __align__(16) u16 Ps[64 * 64];

    int t = threadIdx.x, w = t >> 6, lane = t & 63, l15 = lane & 15, quad = lane >> 4;

    short8 qf[2];
    #pragma unroll
    for (int ds = 0; ds < 2; ds++)
        qf[ds] = *reinterpret_cast<const short8*>(
            &Qp[(qt * 64 + w * 16 + l15) * 64 + ds * 32 + quad * 8]);

    // DMA lane mapping: 1KB seg = 8 rows x 128B; chunk = slot ^ row
    int di = lane >> 3;
    int dc8 = ((lane & 7) ^ di) * 8;

    // K/V fragment read offsets: (row = j*16+l15, chunk c = ds*4+quad)
    int rl = l15 & 7, rh = l15 >> 3;
    int koff[4][2];
    #pragma unroll
    for (int j = 0; j < 4; j++)
        #pragma unroll
        for (int ds = 0; ds < 2; ds++)
            koff[j][ds] = (j * 2 + rh) * 512 + rl * 64 + (((ds * 4 + quad) ^ rl) & 7) * 8;

    int pwt[4];
    #pragma unroll
    for (int j = 0; j < 4; j++)
        pwt[j] = (w * 16 + l15) * 64 +
                 (((2 * j + (quad >> 1)) ^ rl) * 8) + (quad & 1) * 4;
    int prt[2];
    #pragma unroll
    for (int ks = 0; ks < 2; ks++)
        prt[ks] = (w * 16 + l15) * 64 + (((4 * ks + quad) ^ rl) * 8);

    f32x4 acc[4];
    f32x2 lsum2 = (f32x2){0.f, 0.f};
    #pragma unroll
    for (int j = 0; j < 4; j++) acc[j] = (f32x4){0.f, 0.f, 0.f, 0.f};

#define ISSUE_K(KB, HF)                                                      \
    {                                                                        \
        _Pragma("unroll")                                                    \
        for (int sg = 0; sg < 2; sg++) {                                     \
            int seg = w * 2 + sg;                                            \
            gld16(&Kp[((KB) + seg * 8 + di) * 64 + dc8], &Ks[HF][seg * 512]);\
        }                                                                    \
    }
#define ISSUE_V(KB, HF)                                                      \
    {                                                                        \
        _Pragma("unroll")                                                    \
        for (int sg = 0; sg < 2; sg++) {                                     \
            int seg = w * 2 + sg;                                            \
            gld16(&Vp[(seg * 8 + di) * 2048 + (KB) + dc8], &Vt[HF][seg * 512]);\
        }                                                                    \
    }

    // prologue: stage K0/K1 + V0/V1 (kv 0..127), drain, publish
    ISSUE_K(0, 0);  ISSUE_K(64, 1);
    ISSUE_V(0, 0);  ISSUE_V(64, 1);
    __syncthreads();

    for (int kt = 0; kt < 16; kt++) {
        int kbase = kt * 128;

        // S^T = K Q^T over both 64-kv halves: lane owns col q=l15,
        // rows s = hf*64 + 16j + quad*4 + r.
        // (V[kt] loads, issued at the previous bottom barrier, fly under this.)
        f32x4 sc[2][4];
        __builtin_amdgcn_s_setprio(1);
        #pragma unroll
        for (int hf = 0; hf < 2; hf++)
            #pragma unroll
            for (int j = 0; j < 4; j++) {
                f32x4 s0 = (f32x4){0.f, 0.f, 0.f, 0.f};
                #pragma unroll
                for (int ds = 0; ds < 2; ds++) {
                    short8 kf = *reinterpret_cast<const short8*>(&Ks[hf][koff[j][ds]]);
                    s0 = __builtin_amdgcn_mfma_f32_16x16x32_bf16(kf, qf[ds], s0, 0, 0, 0);
                }
                sc[hf][j] = s0;
            }
        __builtin_amdgcn_s_setprio(0);

        // mid barrier: all waves done reading Ks[kt]; drains V[kt] loads
        // (latency hidden under QK above). Ks halves free to restage.
        __syncthreads();
        if (kt < 15) {
            ISSUE_K(kbase + 128, 0);
            ISSUE_K(kbase + 192, 1);
        }

        // softmax + PV per half; Ps reused across halves (wave-private rows,
        // per-wave DS ordering makes the reuse safe).
        #pragma unroll
        for (int hf = 0; hf < 2; hf++) {
            // P = 2^S : RTZ bf16 pack, one b64 write per j; packed lsum adds
            #pragma unroll
            for (int j = 0; j < 4; j++) {
                float p0 = __builtin_amdgcn_exp2f(sc[hf][j][0]);
                float p1 = __builtin_amdgcn_exp2f(sc[hf][j][1]);
                float p2 = __builtin_amdgcn_exp2f(sc[hf][j][2]);
                float p3 = __builtin_amdgcn_exp2f(sc[hf][j][3]);
                lsum2 += (f32x2){p0, p1};
                lsum2 += (f32x2){p2, p3};
                union { float fv; u32 uv; } c0, c1, c2, c3;
                c0.fv = p0; c1.fv = p1; c2.fv = p2; c3.fv = p3;
                uint2 pk;
                pk.x = (c0.uv >> 16) | (c1.uv & 0xffff0000u);
                pk.y = (c2.uv >> 16) | (c3.uv & 0xffff0000u);
                *reinterpret_cast<uint2*>(&Ps[pwt[j]]) = pk;
            }

            // O += P V (wave-private Ps rows; lgkmcnt orders write->read)
            __builtin_amdgcn_s_setprio(1);
            #pragma unroll
            for (int ks = 0; ks < 2; ks++) {
                short8 pf = *reinterpret_cast<const short8*>(&Ps[prt[ks]]);
                #pragma unroll
                for (int j = 0; j < 4; j++) {
                    short8 vf = *reinterpret_cast<const short8*>(&Vt[hf][koff[j][ks]]);
                    acc[j] = __builtin_amdgcn_mfma_f32_16x16x32_bf16(pf, vf, acc[j], 0, 0, 0);
                }
            }
            __builtin_amdgcn_s_setprio(0);
        }

        // bottom barrier: all waves done reading Vt[kt]; drains K[kt+1] loads
        // (latency hidden under softmax+PV above). Vt halves free to restage.
        __syncthreads();
        if (kt < 15) {
            ISSUE_V(kbase + 128, 0);
            ISSUE_V(kbase + 192, 1);
        }
    }
#undef ISSUE_K
#undef ISSUE_V

    // row-sum inverse: after the xor-reduce every lane holds the sum for
    // q-row (w*16 + l15), replicated across quads.
    float s = lsum2.x + lsum2.y;
    s += __shfl_xor(s, 16);
    s += __shfl_xor(s, 32);
    float invf = 1.0f / s;

    // epilogue: O / l, final bf16, direct store. Lane (quad,l15) writes rows
    // quad*4+r -> needs inv for row quad*4+r, held by lane (quad*4+r).
    #pragma unroll
    for (int r = 0; r < 4; r++) {
        float iv = __shfl(invf, quad * 4 + r);
        int srow = qt * 64 + w * 16 + quad * 4 + r;
        #pragma unroll
        for (int j = 0; j < 4; j++)
            Ob[(b_ * 2048 + srow) * 1024 + h * 64 + j * 16 + l15] =
                f2bf(acc[j][r] * iv);
    }
}

// ---------------- Output GEMM, async-pipelined, XCD-swizzled -----------------
// bid = col*32 + row -> A row-stripe pinned to XCD row%8.
__global__ __launch_bounds__(256, 3) void gemm_out(
    const u16* __restrict__ Ob, const u16* __restrict__ Wto,
    const float* __restrict__ bo, float* __restrict__ out)
{
    __shared__ __align__(16) u16 As[2][128 * 32];
    __shared__ __align__(16) u16 Bs[2][128 * 32];
    int t = threadIdx.x;
    int w = t >> 6, lane = t & 63, l15 = lane & 15, quad = lane >> 4;
    int wm = (w >> 1) * 64, wn = (w & 1) * 64;
    int bid = blockIdx.x;
    int row0 = (bid & 31) * 128, col0 = (bid >> 5) * 128;

    int drow = lane >> 2;
    int gc8 = ((lane & 3) ^ (drow & 3) ^ ((drow >> 2) & 3)) * 8;
    int asw = ((quad ^ (l15 & 3) ^ ((l15 >> 2) & 3)) & 3) * 8;

    const u16* Ag = Ob + (row0 + drow) * 1024 + gc8;
    const u16* Bg = Wto + (col0 + drow) * 1024 + gc8;

    f32x4 acc[4][4];
    #pragma unroll
    for (int i = 0; i < 4; i++)
        #pragma unroll
        for (int j = 0; j < 4; j++)
            acc[i][j] = (f32x4){0.f, 0.f, 0.f, 0.f};

    #pragma unroll
    for (int q = 0; q < 2; q++) {
        int rr = w * 32 + q * 16;
        gld16(Ag + rr * 1024, &As[0][rr * 32]);
        gld16(Bg + rr * 1024, &Bs[0][rr * 32]);
    }
    for (int kt = 0; kt < 32; kt++) {
        __syncthreads();
        int cur = kt & 1;
        if (kt < 31) {
            int k0 = (kt + 1) * 32;
            #pragma unroll
            for (int q = 0; q < 2; q++) {
                int rr = w * 32 + q * 16;
                gld16(Ag + rr * 1024 + k0, &As[cur ^ 1][rr * 32]);
                gld16(Bg + rr * 1024 + k0, &Bs[cur ^ 1][rr * 32]);
            }
        }
        short8 a[4], b[4];
        #pragma unroll
        for (int i = 0; i < 4; i++)
            a[i] = *reinterpret_cast<const short8*>(&As[cur][(wm + i * 16 + l15) * 32 + asw]);
        #pragma unroll
        for (int j = 0; j < 4; j++)
            b[j] = *reinterpret_cast<const short8*>(&Bs[cur][(wn + j * 16 + l15) * 32 + asw]);
        #pragma unroll
        for (int i = 0; i < 4; i++)
            #pragma unroll
            for (int j = 0; j < 4; j++)
                acc[i][j] = __builtin_amdgcn_mfma_f32_16x16x32_bf16(a[i], b[j], acc[i][j], 0, 0, 0);
    }
    #pragma unroll
    for (int i = 0; i < 4; i++) {
        int rowb = row0 + wm + i * 16 + quad * 4;
        #pragma unroll
        for (int j = 0; j < 4; j++) {
            int col = col0 + wn + j * 16 + l15;
            float bb = bo[col];
            #pragma unroll
            for (int r = 0; r < 4; r++)
                out[(rowb + r) * 1024 + col] = acc[i][j][r] + bb;
        }
    }
}

extern "C" void kernel_launch(void* const* d_in, const int* in_sizes, int n_in,
                              void* d_out, int out_size, void* d_ws, size_t ws_size,
                              hipStream_t stream) {
    const float* X  = (const float*)d_in[0];
    const float* Wq = (const float*)d_in[1];
    const float* bq = (const float*)d_in[2];
    const float* Wk = (const float*)d_in[3];
    const float* bk = (const float*)d_in[4];
    const float* Wv = (const float*)d_in[5];
    const float* bv = (const float*)d_in[6];
    const float* Wo = (const float*)d_in[7];
    const float* bo = (const float*)d_in[8];
    float* out = (float*)d_out;

    char* ws = (char*)d_ws;
    u16* Xb    = (u16*)(ws);                      // 8 MB [4096,1024]; Ob aliases after use
    u16* Ob    = (u16*)(ws);                      // alias: Xb dead after gemm_qkv
    u16* Wqkv  = (u16*)(ws + (8u  << 20));        // 6 MB [3072,1024] (Wq pre-scaled)
    u16* Wto   = (u16*)(ws + (14u << 20));        // 2 MB [1024,1024]
    float* Bp  = (float*)(ws + (16u << 20));      // 12 KB packed bias (bq pre-scaled)
    u16* Qb    = (u16*)(ws + (17u << 20));        // 8 MB [B,H,S,Dk]
    u16* Kb    = (u16*)(ws + (25u << 20));        // 8 MB [B,H,S,Dk]
    u16* Vtg   = (u16*)(ws + (33u << 20));        // 8 MB [B,H,Dk,S]

    prep     <<<5121, 256, 0, stream>>>(X, Xb, Wq, Wk, Wv, Wo, bq, bk, bv, Wqkv, Wto, Bp);
    gemm_qkv <<<768, 256, 0, stream>>>(Xb, Wqkv, Bp, Qb, Kb, Vtg);
    attn     <<<1024, 256, 0, stream>>>(Qb, Kb, Vtg, Ob);
    gemm_out <<<256, 256, 0, stream>>>(Ob, Wto, bo, out);
}

// Round 9
// 198.318 us; speedup vs baseline: 1.0270x; 1.0270x over previous
//
#include <hip/hip_runtime.h>
#include <hip/hip_bf16.h>

// MHA: B=2, S=2048, D=1024, H=16, Dk=64. fp32 in/out, bf16 MFMA internally.

typedef __attribute__((ext_vector_type(8))) short short8;
typedef __attribute__((ext_vector_type(4))) float f32x4;
typedef __attribute__((ext_vector_type(2))) float f32x2;
typedef unsigned short u16;
typedef unsigned int u32;

static __device__ __forceinline__ u16 f2bf(float f) {
    union { float f; u32 u; } c; c.f = f;
    u32 u = c.u;
    u32 r = u + 0x7fffu + ((u >> 16) & 1u);   // RNE
    return (u16)(r >> 16);
}
static __device__ __forceinline__ float bf2f(u16 x) {
    union { u32 u; float f; } c; c.u = ((u32)x) << 16;
    return c.f;
}

#define GL1(p) ((const __attribute__((address_space(1))) void*)(p))
#define LD3(p) ((__attribute__((address_space(3))) void*)(p))
static __device__ __forceinline__ void gld16(const void* g, void* l) {
    __builtin_amdgcn_global_load_lds(GL1(g), LD3(l), 16, 0, 0);
}

// log2(e)/8 — folded into Wq/bq in prep, so Q comes out pre-scaled
#define Q_PRESCALE 0.18033688011112042f

// ---------------- prep -------------------------------------------------------
__global__ __launch_bounds__(256) void prep(
    const float* __restrict__ X, u16* __restrict__ Xb,
    const float* __restrict__ Wq, const float* __restrict__ Wk,
    const float* __restrict__ Wv, const float* __restrict__ Wo,
    const float* __restrict__ bq, const float* __restrict__ bk,
    const float* __restrict__ bv,
    u16* __restrict__ Wqkv, u16* __restrict__ Wto, float* __restrict__ Bp)
{
    int id = blockIdx.x;
    int t = threadIdx.x;
    if (id == 5120) {
        for (int i = t; i < 3072; i += 256) {
            int wsel = i >> 10, c = i & 1023;
            float v = (wsel == 0) ? bq[c] * Q_PRESCALE : (wsel == 1 ? bk[c] : bv[c]);
            Bp[i] = v;
        }
        return;
    }
    if (id >= 1024) {
        int i = (id - 1024) * 1024 + t * 4;
        float4 v = *reinterpret_cast<const float4*>(X + i);
        ushort4 o;
        o.x = f2bf(v.x); o.y = f2bf(v.y); o.z = f2bf(v.z); o.w = f2bf(v.w);
        *reinterpret_cast<ushort4*>(Xb + i) = o;
        return;
    }
    int which = id >> 8;
    const float* W; u16* T; float sc;
    switch (which) {
        case 0: W = Wq; T = Wqkv;                sc = Q_PRESCALE; break;
        case 1: W = Wk; T = Wqkv + 1024 * 1024;  sc = 1.0f; break;
        case 2: W = Wv; T = Wqkv + 2048 * 1024;  sc = 1.0f; break;
        default: W = Wo; T = Wto;                sc = 1.0f; break;
    }
    int rem = id & 255;
    int n0 = (rem & 15) * 64, k0 = (rem >> 4) * 64;
    __shared__ float tile[64][65];
    int r = t / 16, c4 = (t % 16) * 4;
    #pragma unroll
    for (int p = 0; p < 4; p++) {
        int row = p * 16 + r;
        float4 v = *reinterpret_cast<const float4*>(W + (k0 + row) * 1024 + n0 + c4);
        tile[row][c4 + 0] = v.x * sc; tile[row][c4 + 1] = v.y * sc;
        tile[row][c4 + 2] = v.z * sc; tile[row][c4 + 3] = v.w * sc;
    }
    __syncthreads();
    #pragma unroll
    for (int p = 0; p < 4; p++) {
        int nrow = p * 16 + r;
        ushort4 o;
        o.x = f2bf(tile[c4 + 0][nrow]); o.y = f2bf(tile[c4 + 1][nrow]);
        o.z = f2bf(tile[c4 + 2][nrow]); o.w = f2bf(tile[c4 + 3][nrow]);
        *reinterpret_cast<ushort4*>(T + (n0 + nrow) * 1024 + k0 + c4) = o;
    }
}

// ---------------- fused QKV GEMM, async-pipelined, XCD-swizzled --------------
// bid = col*32 + row -> bid%8 = row%8: all 24 col-blocks sharing an A row-
// stripe land on ONE XCD (per-XCD L2 working set: A 1MB + B, vs 8x A refetch).
__global__ __launch_bounds__(256, 3) void gemm_qkv(
    const u16* __restrict__ Xb, const u16* __restrict__ Wqkv,
    const float* __restrict__ Bp,
    u16* __restrict__ Qb, u16* __restrict__ Kb, u16* __restrict__ Vtg)
{
    __shared__ __align__(16) u16 As[2][128 * 32];
    __shared__ __align__(16) u16 Bs[2][128 * 32];
    int t = threadIdx.x;
    int w = t >> 6, lane = t & 63, l15 = lane & 15, quad = lane >> 4;
    int wm = (w >> 1) * 64, wn = (w & 1) * 64;
    int bid = blockIdx.x;
    int row0 = (bid & 31) * 128, col0 = (bid >> 5) * 128;

    int drow = lane >> 2;
    int gc8 = ((lane & 3) ^ (drow & 3) ^ ((drow >> 2) & 3)) * 8;
    int asw = ((quad ^ (l15 & 3) ^ ((l15 >> 2) & 3)) & 3) * 8;

    const u16* Ag = Xb + (row0 + drow) * 1024 + gc8;
    const u16* Bg = Wqkv + (col0 + drow) * 1024 + gc8;

    f32x4 acc[4][4];
    #pragma unroll
    for (int i = 0; i < 4; i++)
        #pragma unroll
        for (int j = 0; j < 4; j++)
            acc[i][j] = (f32x4){0.f, 0.f, 0.f, 0.f};

    #pragma unroll
    for (int q = 0; q < 2; q++) {
        int rr = w * 32 + q * 16;
        gld16(Ag + rr * 1024, &As[0][rr * 32]);
        gld16(Bg + rr * 1024, &Bs[0][rr * 32]);
    }
    for (int kt = 0; kt < 32; kt++) {
        __syncthreads();
        int cur = kt & 1;
        if (kt < 31) {
            int k0 = (kt + 1) * 32;
            #pragma unroll
            for (int q = 0; q < 2; q++) {
                int rr = w * 32 + q * 16;
                gld16(Ag + rr * 1024 + k0, &As[cur ^ 1][rr * 32]);
                gld16(Bg + rr * 1024 + k0, &Bs[cur ^ 1][rr * 32]);
            }
        }
        short8 a[4], b[4];
        #pragma unroll
        for (int i = 0; i < 4; i++)
            a[i] = *reinterpret_cast<const short8*>(&As[cur][(wm + i * 16 + l15) * 32 + asw]);
        #pragma unroll
        for (int j = 0; j < 4; j++)
            b[j] = *reinterpret_cast<const short8*>(&Bs[cur][(wn + j * 16 + l15) * 32 + asw]);
        #pragma unroll
        for (int i = 0; i < 4; i++)
            #pragma unroll
            for (int j = 0; j < 4; j++)
                acc[i][j] = __builtin_amdgcn_mfma_f32_16x16x32_bf16(a[i], b[j], acc[i][j], 0, 0, 0);
    }

    int osel = col0 >> 10;                 // 0=Q 1=K 2=V (block-uniform)
    if (osel == 2) {
        #pragma unroll
        for (int i = 0; i < 4; i++) {
            int gr = row0 + wm + i * 16 + quad * 4;
            int b_ = gr >> 11, s = gr & 2047;
            #pragma unroll
            for (int j = 0; j < 4; j++) {
                int col = col0 + wn + j * 16 + l15;
                int c = col & 1023, h = c >> 6, d = c & 63;
                float bb = Bp[col];
                ushort4 pk;
                pk.x = f2bf(acc[i][j][0] + bb);
                pk.y = f2bf(acc[i][j][1] + bb);
                pk.z = f2bf(acc[i][j][2] + bb);
                pk.w = f2bf(acc[i][j][3] + bb);
                *reinterpret_cast<ushort4*>(&Vtg[((b_ * 16 + h) * 64 + d) * 2048 + s]) = pk;
            }
        }
    } else {
        u16* dst = osel ? Kb : Qb;
        #pragma unroll
        for (int i = 0; i < 4; i++) {
            int rowb = row0 + wm + i * 16 + quad * 4;
            #pragma unroll
            for (int j = 0; j < 4; j++) {
                int col = col0 + wn + j * 16 + l15;
                int c = col & 1023, h = c >> 6, d = c & 63;
                float bb = Bp[col];
                #pragma unroll
                for (int r = 0; r < 4; r++) {
                    int gr = rowb + r;
                    int b_ = gr >> 11, s = gr & 2047;
                    dst[(((b_ << 4) + h) * 2048 + s) * 64 + d] = f2bf(acc[i][j][r] + bb);
                }
            }
        }
    }
}

// ---------------- Attention, full-K per block, XCD-swizzled ------------------
// v10: r8 structure (KVBLK=128, two 64-kv halves, 40KB LDS, 4 blocks/CU)
//      + v_perm_b32 bf16 pack (bit-identical to shift/and/or, 1 op vs 3).
__global__ __launch_bounds__(256) void attn(
    const u16* __restrict__ Qb, const u16* __restrict__ Kb,
    const u16* __restrict__ Vtg, u16* __restrict__ Ob)
{
    int bid = blockIdx.x;
    int bh = bid & 31, qt = bid >> 5;      // qt in [0,32), 64 q-rows each
    int b_ = bh >> 4, h = bh & 15;
    const u16* Qp = Qb + bh * (2048 * 64);
    const u16* Kp = Kb + bh * (2048 * 64);
    const u16* Vp = Vtg + bh * (64 * 2048);

    __shared__ __align__(16) u16 Ks[2][64 * 64];
    __shared__ __align__(16) u16 Vt[2][64 * 64];
    __shared__ __align__(16) u16 Ps[64 * 64];

    int t = threadIdx.x, w = t >> 6, lane = t & 63, l15 = lane & 15, quad = lane >> 4;

    short8 qf[2];
    #pragma unroll
    for (int ds = 0; ds < 2; ds++)
        qf[ds] = *reinterpret_cast<const short8*>(
            &Qp[(qt * 64 + w * 16 + l15) * 64 + ds * 32 + quad * 8]);

    // DMA lane mapping: 1KB seg = 8 rows x 128B; chunk = slot ^ row
    int di = lane >> 3;
    int dc8 = ((lane & 7) ^ di) * 8;

    // K/V fragment read offsets: (row = j*16+l15, chunk c = ds*4+quad)
    int rl = l15 & 7, rh = l15 >> 3;
    int koff[4][2];
    #pragma unroll
    for (int j = 0; j < 4; j++)
        #pragma unroll
        for (int ds = 0; ds < 2; ds++)
            koff[j][ds] = (j * 2 + rh) * 512 + rl * 64 + (((ds * 4 + quad) ^ rl) & 7) * 8;

    int pwt[4];
    #pragma unroll
    for (int j = 0; j < 4; j++)
        pwt[j] = (w * 16 + l15) * 64 +
                 (((2 * j + (quad >> 1)) ^ rl) * 8) + (quad & 1) * 4;
    int prt[2];
    #pragma unroll
    for (int ks = 0; ks < 2; ks++)
        prt[ks] = (w * 16 + l15) * 64 + (((4 * ks + quad) ^ rl) * 8);

    f32x4 acc[4];
    f32x2 lsum2 = (f32x2){0.f, 0.f};
    #pragma unroll
    for (int j = 0; j < 4; j++) acc[j] = (f32x4){0.f, 0.f, 0.f, 0.f};

#define ISSUE_K(KB, HF)                                                      \
    {                                                                        \
        _Pragma("unroll")                                                    \
        for (int sg = 0; sg < 2; sg++) {                                     \
            int seg = w * 2 + sg;                                            \
            gld16(&Kp[((KB) + seg * 8 + di) * 64 + dc8], &Ks[HF][seg * 512]);\
        }                                                                    \
    }
#define ISSUE_V(KB, HF)                                                      \
    {                                                                        \
        _Pragma("unroll")                                                    \
        for (int sg = 0; sg < 2; sg++) {                                     \
            int seg = w * 2 + sg;                                            \
            gld16(&Vp[(seg * 8 + di) * 2048 + (KB) + dc8], &Vt[HF][seg * 512]);\
        }                                                                    \
    }

    // prologue: stage K0/K1 + V0/V1 (kv 0..127), drain, publish
    ISSUE_K(0, 0);  ISSUE_K(64, 1);
    ISSUE_V(0, 0);  ISSUE_V(64, 1);
    __syncthreads();

    for (int kt = 0; kt < 16; kt++) {
        int kbase = kt * 128;

        // S^T = K Q^T over both 64-kv halves: lane owns col q=l15,
        // rows s = hf*64 + 16j + quad*4 + r.
        // (V[kt] loads, issued at the previous bottom barrier, fly under this.)
        f32x4 sc[2][4];
        __builtin_amdgcn_s_setprio(1);
        #pragma unroll
        for (int hf = 0; hf < 2; hf++)
            #pragma unroll
            for (int j = 0; j < 4; j++) {
                f32x4 s0 = (f32x4){0.f, 0.f, 0.f, 0.f};
                #pragma unroll
                for (int ds = 0; ds < 2; ds++) {
                    short8 kf = *reinterpret_cast<const short8*>(&Ks[hf][koff[j][ds]]);
                    s0 = __builtin_amdgcn_mfma_f32_16x16x32_bf16(kf, qf[ds], s0, 0, 0, 0);
                }
                sc[hf][j] = s0;
            }
        __builtin_amdgcn_s_setprio(0);

        // mid barrier: all waves done reading Ks[kt]; drains V[kt] loads
        // (latency hidden under QK above). Ks halves free to restage.
        __syncthreads();
        if (kt < 15) {
            ISSUE_K(kbase + 128, 0);
            ISSUE_K(kbase + 192, 1);
        }

        // softmax + PV per half; Ps reused across halves (wave-private rows,
        // per-wave DS ordering makes the reuse safe).
        #pragma unroll
        for (int hf = 0; hf < 2; hf++) {
            // P = 2^S : RTZ bf16 pack via v_perm_b32 (bit-identical to
            // shift/and/or), one b64 write per j; packed lsum adds
            #pragma unroll
            for (int j = 0; j < 4; j++) {
                float p0 = __builtin_amdgcn_exp2f(sc[hf][j][0]);
                float p1 = __builtin_amdgcn_exp2f(sc[hf][j][1]);
                float p2 = __builtin_amdgcn_exp2f(sc[hf][j][2]);
                float p3 = __builtin_amdgcn_exp2f(sc[hf][j][3]);
                lsum2 += (f32x2){p0, p1};
                lsum2 += (f32x2){p2, p3};
                union { float fv; u32 uv; } c0, c1, c2, c3;
                c0.fv = p0; c1.fv = p1; c2.fv = p2; c3.fv = p3;
                uint2 pk;
                pk.x = __builtin_amdgcn_perm(c1.uv, c0.uv, 0x07060302u);
                pk.y = __builtin_amdgcn_perm(c3.uv, c2.uv, 0x07060302u);
                *reinterpret_cast<uint2*>(&Ps[pwt[j]]) = pk;
            }

            // O += P V (wave-private Ps rows; lgkmcnt orders write->read)
            __builtin_amdgcn_s_setprio(1);
            #pragma unroll
            for (int ks = 0; ks < 2; ks++) {
                short8 pf = *reinterpret_cast<const short8*>(&Ps[prt[ks]]);
                #pragma unroll
                for (int j = 0; j < 4; j++) {
                    short8 vf = *reinterpret_cast<const short8*>(&Vt[hf][koff[j][ks]]);
                    acc[j] = __builtin_amdgcn_mfma_f32_16x16x32_bf16(pf, vf, acc[j], 0, 0, 0);
                }
            }
            __builtin_amdgcn_s_setprio(0);
        }

        // bottom barrier: all waves done reading Vt[kt]; drains K[kt+1] loads
        // (latency hidden under softmax+PV above). Vt halves free to restage.
        __syncthreads();
        if (kt < 15) {
            ISSUE_V(kbase + 128, 0);
            ISSUE_V(kbase + 192, 1);
        }
    }
#undef ISSUE_K
#undef ISSUE_V

    // row-sum inverse: after the xor-reduce every lane holds the sum for
    // q-row (w*16 + l15), replicated across quads.
    float s = lsum2.x + lsum2.y;
    s += __shfl_xor(s, 16);
    s += __shfl_xor(s, 32);
    float invf = 1.0f / s;

    // epilogue: O / l, final bf16, direct store. Lane (quad,l15) writes rows
    // quad*4+r -> needs inv for row quad*4+r, held by lane (quad*4+r).
    #pragma unroll
    for (int r = 0; r < 4; r++) {
        float iv = __shfl(invf, quad * 4 + r);
        int srow = qt * 64 + w * 16 + quad * 4 + r;
        #pragma unroll
        for (int j = 0; j < 4; j++)
            Ob[(b_ * 2048 + srow) * 1024 + h * 64 + j * 16 + l15] =
                f2bf(acc[j][r] * iv);
    }
}

// ---------------- Output GEMM, async-pipelined, XCD-swizzled -----------------
// v2: 128x64 tiles, grid 512 = 2 blocks/CU (was 256 = 1/CU: a barrier-per-
// iteration loop with no co-resident block leaves every vmcnt(0) drain fully
// exposed — r6's attn showed the same disease at 2/CU). A path and swizzles
// unchanged; B tile halved (wn=(w&1)*32, Bs 64x32, one B-stage gld16/wave,
// acc[4][2]). bid = col*512-grid -> A row-stripe still pinned to XCD row%8.
__global__ __launch_bounds__(256, 3) void gemm_out(
    const u16* __restrict__ Ob, const u16* __restrict__ Wto,
    const float* __restrict__ bo, float* __restrict__ out)
{
    __shared__ __align__(16) u16 As[2][128 * 32];
    __shared__ __align__(16) u16 Bs[2][64 * 32];
    int t = threadIdx.x;
    int w = t >> 6, lane = t & 63, l15 = lane & 15, quad = lane >> 4;
    int wm = (w >> 1) * 64, wn = (w & 1) * 32;
    int bid = blockIdx.x;
    int row0 = (bid & 31) * 128, col0 = (bid >> 5) * 64;

    int drow = lane >> 2;
    int gc8 = ((lane & 3) ^ (drow & 3) ^ ((drow >> 2) & 3)) * 8;
    int asw = ((quad ^ (l15 & 3) ^ ((l15 >> 2) & 3)) & 3) * 8;

    const u16* Ag = Ob + (row0 + drow) * 1024 + gc8;
    const u16* Bg = Wto + (col0 + drow) * 1024 + gc8;

    f32x4 acc[4][2];
    #pragma unroll
    for (int i = 0; i < 4; i++)
        #pragma unroll
        for (int j = 0; j < 2; j++)
            acc[i][j] = (f32x4){0.f, 0.f, 0.f, 0.f};

    #pragma unroll
    for (int q = 0; q < 2; q++) {
        int rr = w * 32 + q * 16;
        gld16(Ag + rr * 1024, &As[0][rr * 32]);
    }
    {
        int rr = w * 16;
        gld16(Bg + rr * 1024, &Bs[0][rr * 32]);
    }
    for (int kt = 0; kt < 32; kt++) {
        __syncthreads();
        int cur = kt & 1;
        if (kt < 31) {
            int k0 = (kt + 1) * 32;
            #pragma unroll
            for (int q = 0; q < 2; q++) {
                int rr = w * 32 + q * 16;
                gld16(Ag + rr * 1024 + k0, &As[cur ^ 1][rr * 32]);
            }
            int rr = w * 16;
            gld16(Bg + rr * 1024 + k0, &Bs[cur ^ 1][rr * 32]);
        }
        short8 a[4], b[2];
        #pragma unroll
        for (int i = 0; i < 4; i++)
            a[i] = *reinterpret_cast<const short8*>(&As[cur][(wm + i * 16 + l15) * 32 + asw]);
        #pragma unroll
        for (int j = 0; j < 2; j++)
            b[j] = *reinterpret_cast<const short8*>(&Bs[cur][(wn + j * 16 + l15) * 32 + asw]);
        #pragma unroll
        for (int i = 0; i < 4; i++)
            #pragma unroll
            for (int j = 0; j < 2; j++)
                acc[i][j] = __builtin_amdgcn_mfma_f32_16x16x32_bf16(a[i], b[j], acc[i][j], 0, 0, 0);
    }
    #pragma unroll
    for (int i = 0; i < 4; i++) {
        int rowb = row0 + wm + i * 16 + quad * 4;
        #pragma unroll
        for (int j = 0; j < 2; j++) {
            int col = col0 + wn + j * 16 + l15;
            float bb = bo[col];
            #pragma unroll
            for (int r = 0; r < 4; r++)
                out[(rowb + r) * 1024 + col] = acc[i][j][r] + bb;
        }
    }
}

extern "C" void kernel_launch(void* const* d_in, const int* in_sizes, int n_in,
                              void* d_out, int out_size, void* d_ws, size_t ws_size,
                              hipStream_t stream) {
    const float* X  = (const float*)d_in[0];
    const float* Wq = (const float*)d_in[1];
    const float* bq = (const float*)d_in[2];
    const float* Wk = (const float*)d_in[3];
    const float* bk = (const float*)d_in[4];
    const float* Wv = (const float*)d_in[5];
    const float* bv = (const float*)d_in[6];
    const float* Wo = (const float*)d_in[7];
    const float* bo = (const float*)d_in[8];
    float* out = (float*)d_out;

    char* ws = (char*)d_ws;
    u16* Xb    = (u16*)(ws);                      // 8 MB [4096,1024]; Ob aliases after use
    u16* Ob    = (u16*)(ws);                      // alias: Xb dead after gemm_qkv
    u16* Wqkv  = (u16*)(ws + (8u  << 20));        // 6 MB [3072,1024] (Wq pre-scaled)
    u16* Wto   = (u16*)(ws + (14u << 20));        // 2 MB [1024,1024]
    float* Bp  = (float*)(ws + (16u << 20));      // 12 KB packed bias (bq pre-scaled)
    u16* Qb    = (u16*)(ws + (17u << 20));        // 8 MB [B,H,S,Dk]
    u16* Kb    = (u16*)(ws + (25u << 20));        // 8 MB [B,H,S,Dk]
    u16* Vtg   = (u16*)(ws + (33u << 20));        // 8 MB [B,H,Dk,S]

    prep     <<<5121, 256, 0, stream>>>(X, Xb, Wq, Wk, Wv, Wo, bq, bk, bv, Wqkv, Wto, Bp);
    gemm_qkv <<<768, 256, 0, stream>>>(Xb, Wqkv, Bp, Qb, Kb, Vtg);
    attn     <<<1024, 256, 0, stream>>>(Qb, Kb, Vtg, Ob);
    gemm_out <<<512, 256, 0, stream>>>(Ob, Wto, bo, out);
}

// Round 10
// 194.769 us; speedup vs baseline: 1.0457x; 1.0182x over previous
//
#include <hip/hip_runtime.h>
#include <hip/hip_bf16.h>

// MHA: B=2, S=2048, D=1024, H=16, Dk=64. fp32 in/out, bf16 MFMA internally.

typedef __attribute__((ext_vector_type(8))) short short8;
typedef __attribute__((ext_vector_type(4))) float f32x4;
typedef __attribute__((ext_vector_type(2))) float f32x2;
typedef unsigned short u16;
typedef unsigned int u32;

static __device__ __forceinline__ u16 f2bf(float f) {
    union { float f; u32 u; } c; c.f = f;
    u32 u = c.u;
    u32 r = u + 0x7fffu + ((u >> 16) & 1u);   // RNE
    return (u16)(r >> 16);
}
static __device__ __forceinline__ float bf2f(u16 x) {
    union { u32 u; float f; } c; c.u = ((u32)x) << 16;
    return c.f;
}

#define GL1(p) ((const __attribute__((address_space(1))) void*)(p))
#define LD3(p) ((__attribute__((address_space(3))) void*)(p))
static __device__ __forceinline__ void gld16(const void* g, void* l) {
    __builtin_amdgcn_global_load_lds(GL1(g), LD3(l), 16, 0, 0);
}

// log2(e)/8 — folded into Wq/bq in prep, so Q comes out pre-scaled
#define Q_PRESCALE 0.18033688011112042f

// ---------------- prep -------------------------------------------------------
__global__ __launch_bounds__(256) void prep(
    const float* __restrict__ X, u16* __restrict__ Xb,
    const float* __restrict__ Wq, const float* __restrict__ Wk,
    const float* __restrict__ Wv, const float* __restrict__ Wo,
    const float* __restrict__ bq, const float* __restrict__ bk,
    const float* __restrict__ bv,
    u16* __restrict__ Wqkv, u16* __restrict__ Wto, float* __restrict__ Bp)
{
    int id = blockIdx.x;
    int t = threadIdx.x;
    if (id == 5120) {
        for (int i = t; i < 3072; i += 256) {
            int wsel = i >> 10, c = i & 1023;
            float v = (wsel == 0) ? bq[c] * Q_PRESCALE : (wsel == 1 ? bk[c] : bv[c]);
            Bp[i] = v;
        }
        return;
    }
    if (id >= 1024) {
        int i = (id - 1024) * 1024 + t * 4;
        float4 v = *reinterpret_cast<const float4*>(X + i);
        ushort4 o;
        o.x = f2bf(v.x); o.y = f2bf(v.y); o.z = f2bf(v.z); o.w = f2bf(v.w);
        *reinterpret_cast<ushort4*>(Xb + i) = o;
        return;
    }
    int which = id >> 8;
    const float* W; u16* T; float sc;
    switch (which) {
        case 0: W = Wq; T = Wqkv;                sc = Q_PRESCALE; break;
        case 1: W = Wk; T = Wqkv + 1024 * 1024;  sc = 1.0f; break;
        case 2: W = Wv; T = Wqkv + 2048 * 1024;  sc = 1.0f; break;
        default: W = Wo; T = Wto;                sc = 1.0f; break;
    }
    int rem = id & 255;
    int n0 = (rem & 15) * 64, k0 = (rem >> 4) * 64;
    __shared__ float tile[64][65];
    int r = t / 16, c4 = (t % 16) * 4;
    #pragma unroll
    for (int p = 0; p < 4; p++) {
        int row = p * 16 + r;
        float4 v = *reinterpret_cast<const float4*>(W + (k0 + row) * 1024 + n0 + c4);
        tile[row][c4 + 0] = v.x * sc; tile[row][c4 + 1] = v.y * sc;
        tile[row][c4 + 2] = v.z * sc; tile[row][c4 + 3] = v.w * sc;
    }
    __syncthreads();
    #pragma unroll
    for (int p = 0; p < 4; p++) {
        int nrow = p * 16 + r;
        ushort4 o;
        o.x = f2bf(tile[c4 + 0][nrow]); o.y = f2bf(tile[c4 + 1][nrow]);
        o.z = f2bf(tile[c4 + 2][nrow]); o.w = f2bf(tile[c4 + 3][nrow]);
        *reinterpret_cast<ushort4*>(T + (n0 + nrow) * 1024 + k0 + c4) = o;
    }
}

// ---------------- fused QKV GEMM, async-pipelined, XCD-swizzled --------------
// bid = col*32 + row -> bid%8 = row%8: all 24 col-blocks sharing an A row-
// stripe land on ONE XCD (per-XCD L2 working set: A 1MB + B, vs 8x A refetch).
__global__ __launch_bounds__(256, 3) void gemm_qkv(
    const u16* __restrict__ Xb, const u16* __restrict__ Wqkv,
    const float* __restrict__ Bp,
    u16* __restrict__ Qb, u16* __restrict__ Kb, u16* __restrict__ Vtg)
{
    __shared__ __align__(16) u16 As[2][128 * 32];
    __shared__ __align__(16) u16 Bs[2][128 * 32];
    int t = threadIdx.x;
    int w = t >> 6, lane = t & 63, l15 = lane & 15, quad = lane >> 4;
    int wm = (w >> 1) * 64, wn = (w & 1) * 64;
    int bid = blockIdx.x;
    int row0 = (bid & 31) * 128, col0 = (bid >> 5) * 128;

    int drow = lane >> 2;
    int gc8 = ((lane & 3) ^ (drow & 3) ^ ((drow >> 2) & 3)) * 8;
    int asw = ((quad ^ (l15 & 3) ^ ((l15 >> 2) & 3)) & 3) * 8;

    const u16* Ag = Xb + (row0 + drow) * 1024 + gc8;
    const u16* Bg = Wqkv + (col0 + drow) * 1024 + gc8;

    f32x4 acc[4][4];
    #pragma unroll
    for (int i = 0; i < 4; i++)
        #pragma unroll
        for (int j = 0; j < 4; j++)
            acc[i][j] = (f32x4){0.f, 0.f, 0.f, 0.f};

    #pragma unroll
    for (int q = 0; q < 2; q++) {
        int rr = w * 32 + q * 16;
        gld16(Ag + rr * 1024, &As[0][rr * 32]);
        gld16(Bg + rr * 1024, &Bs[0][rr * 32]);
    }
    for (int kt = 0; kt < 32; kt++) {
        __syncthreads();
        int cur = kt & 1;
        if (kt < 31) {
            int k0 = (kt + 1) * 32;
            #pragma unroll
            for (int q = 0; q < 2; q++) {
                int rr = w * 32 + q * 16;
                gld16(Ag + rr * 1024 + k0, &As[cur ^ 1][rr * 32]);
                gld16(Bg + rr * 1024 + k0, &Bs[cur ^ 1][rr * 32]);
            }
        }
        short8 a[4], b[4];
        #pragma unroll
        for (int i = 0; i < 4; i++)
            a[i] = *reinterpret_cast<const short8*>(&As[cur][(wm + i * 16 + l15) * 32 + asw]);
        #pragma unroll
        for (int j = 0; j < 4; j++)
            b[j] = *reinterpret_cast<const short8*>(&Bs[cur][(wn + j * 16 + l15) * 32 + asw]);
        #pragma unroll
        for (int i = 0; i < 4; i++)
            #pragma unroll
            for (int j = 0; j < 4; j++)
                acc[i][j] = __builtin_amdgcn_mfma_f32_16x16x32_bf16(a[i], b[j], acc[i][j], 0, 0, 0);
    }

    int osel = col0 >> 10;                 // 0=Q 1=K 2=V (block-uniform)
    if (osel == 2) {
        #pragma unroll
        for (int i = 0; i < 4; i++) {
            int gr = row0 + wm + i * 16 + quad * 4;
            int b_ = gr >> 11, s = gr & 2047;
            #pragma unroll
            for (int j = 0; j < 4; j++) {
                int col = col0 + wn + j * 16 + l15;
                int c = col & 1023, h = c >> 6, d = c & 63;
                float bb = Bp[col];
                ushort4 pk;
                pk.x = f2bf(acc[i][j][0] + bb);
                pk.y = f2bf(acc[i][j][1] + bb);
                pk.z = f2bf(acc[i][j][2] + bb);
                pk.w = f2bf(acc[i][j][3] + bb);
                *reinterpret_cast<ushort4*>(&Vtg[((b_ * 16 + h) * 64 + d) * 2048 + s]) = pk;
            }
        }
    } else {
        u16* dst = osel ? Kb : Qb;
        #pragma unroll
        for (int i = 0; i < 4; i++) {
            int rowb = row0 + wm + i * 16 + quad * 4;
            #pragma unroll
            for (int j = 0; j < 4; j++) {
                int col = col0 + wn + j * 16 + l15;
                int c = col & 1023, h = c >> 6, d = c & 63;
                float bb = Bp[col];
                #pragma unroll
                for (int r = 0; r < 4; r++) {
                    int gr = rowb + r;
                    int b_ = gr >> 11, s = gr & 2047;
                    dst[(((b_ << 4) + h) * 2048 + s) * 64 + d] = f2bf(acc[i][j][r] + bb);
                }
            }
        }
    }
}

// ---------------- Attention, full-K per block, XCD-swizzled ------------------
// v11: r9 structure (KVBLK=128, two 64-kv halves, 40KB LDS, 4 blocks/CU,
//      v_perm_b32 pack) + lsum via ones-column MFMA: accl = mfma(pf, 1, accl)
//      puts row-sums on the (24%-utilized) matrix pipe, deletes 16 packed
//      adds/iter AND the entire cross-lane epilogue — accl[r] at lane
//      (quad,l15) is the row-sum for q-row quad*4+r, the exact row this lane
//      writes. Denominator now uses the same bf16-rounded P as the numerator.
__global__ __launch_bounds__(256) void attn(
    const u16* __restrict__ Qb, const u16* __restrict__ Kb,
    const u16* __restrict__ Vtg, u16* __restrict__ Ob)
{
    int bid = blockIdx.x;
    int bh = bid & 31, qt = bid >> 5;      // qt in [0,32), 64 q-rows each
    int b_ = bh >> 4, h = bh & 15;
    const u16* Qp = Qb + bh * (2048 * 64);
    const u16* Kp = Kb + bh * (2048 * 64);
    const u16* Vp = Vtg + bh * (64 * 2048);

    __shared__ __align__(16) u16 Ks[2][64 * 64];
    __shared__ __align__(16) u16 Vt[2][64 * 64];
    __shared__ __align__(16) u16 Ps[64 * 64];

    int t = threadIdx.x, w = t >> 6, lane = t & 63, l15 = lane & 15, quad = lane >> 4;

    short8 qf[2];
    #pragma unroll
    for (int ds = 0; ds < 2; ds++)
        qf[ds] = *reinterpret_cast<const short8*>(
            &Qp[(qt * 64 + w * 16 + l15) * 64 + ds * 32 + quad * 8]);

    // DMA lane mapping: 1KB seg = 8 rows x 128B; chunk = slot ^ row
    int di = lane >> 3;
    int dc8 = ((lane & 7) ^ di) * 8;

    // K/V fragment read offsets: (row = j*16+l15, chunk c = ds*4+quad)
    int rl = l15 & 7, rh = l15 >> 3;
    int koff[4][2];
    #pragma unroll
    for (int j = 0; j < 4; j++)
        #pragma unroll
        for (int ds = 0; ds < 2; ds++)
            koff[j][ds] = (j * 2 + rh) * 512 + rl * 64 + (((ds * 4 + quad) ^ rl) & 7) * 8;

    int pwt[4];
    #pragma unroll
    for (int j = 0; j < 4; j++)
        pwt[j] = (w * 16 + l15) * 64 +
                 (((2 * j + (quad >> 1)) ^ rl) * 8) + (quad & 1) * 4;
    int prt[2];
    #pragma unroll
    for (int ks = 0; ks < 2; ks++)
        prt[ks] = (w * 16 + l15) * 64 + (((4 * ks + quad) ^ rl) * 8);

    f32x4 acc[4];
    f32x4 accl = (f32x4){0.f, 0.f, 0.f, 0.f};
    #pragma unroll
    for (int j = 0; j < 4; j++) acc[j] = (f32x4){0.f, 0.f, 0.f, 0.f};

    const short8 ones8 = {16256, 16256, 16256, 16256, 16256, 16256, 16256, 16256};

#define ISSUE_K(KB, HF)                                                      \
    {                                                                        \
        _Pragma("unroll")                                                    \
        for (int sg = 0; sg < 2; sg++) {                                     \
            int seg = w * 2 + sg;                                            \
            gld16(&Kp[((KB) + seg * 8 + di) * 64 + dc8], &Ks[HF][seg * 512]);\
        }                                                                    \
    }
#define ISSUE_V(KB, HF)                                                      \
    {                                                                        \
        _Pragma("unroll")                                                    \
        for (int sg = 0; sg < 2; sg++) {                                     \
            int seg = w * 2 + sg;                                            \
            gld16(&Vp[(seg * 8 + di) * 2048 + (KB) + dc8], &Vt[HF][seg * 512]);\
        }                                                                    \
    }

    // prologue: stage K0/K1 + V0/V1 (kv 0..127), drain, publish
    ISSUE_K(0, 0);  ISSUE_K(64, 1);
    ISSUE_V(0, 0);  ISSUE_V(64, 1);
    __syncthreads();

    for (int kt = 0; kt < 16; kt++) {
        int kbase = kt * 128;

        // S^T = K Q^T over both 64-kv halves: lane owns col q=l15,
        // rows s = hf*64 + 16j + quad*4 + r.
        // (V[kt] loads, issued at the previous bottom barrier, fly under this.)
        f32x4 sc[2][4];
        __builtin_amdgcn_s_setprio(1);
        #pragma unroll
        for (int hf = 0; hf < 2; hf++)
            #pragma unroll
            for (int j = 0; j < 4; j++) {
                f32x4 s0 = (f32x4){0.f, 0.f, 0.f, 0.f};
                #pragma unroll
                for (int ds = 0; ds < 2; ds++) {
                    short8 kf = *reinterpret_cast<const short8*>(&Ks[hf][koff[j][ds]]);
                    s0 = __builtin_amdgcn_mfma_f32_16x16x32_bf16(kf, qf[ds], s0, 0, 0, 0);
                }
                sc[hf][j] = s0;
            }
        __builtin_amdgcn_s_setprio(0);

        // mid barrier: all waves done reading Ks[kt]; drains V[kt] loads
        // (latency hidden under QK above). Ks halves free to restage.
        __syncthreads();
        if (kt < 15) {
            ISSUE_K(kbase + 128, 0);
            ISSUE_K(kbase + 192, 1);
        }

        // softmax + PV per half; Ps reused across halves (wave-private rows,
        // per-wave DS ordering makes the reuse safe).
        #pragma unroll
        for (int hf = 0; hf < 2; hf++) {
            // P = 2^S : RTZ bf16 pack via v_perm_b32 (bit-identical to
            // shift/and/or), one b64 write per j
            #pragma unroll
            for (int j = 0; j < 4; j++) {
                float p0 = __builtin_amdgcn_exp2f(sc[hf][j][0]);
                float p1 = __builtin_amdgcn_exp2f(sc[hf][j][1]);
                float p2 = __builtin_amdgcn_exp2f(sc[hf][j][2]);
                float p3 = __builtin_amdgcn_exp2f(sc[hf][j][3]);
                union { float fv; u32 uv; } c0, c1, c2, c3;
                c0.fv = p0; c1.fv = p1; c2.fv = p2; c3.fv = p3;
                uint2 pk;
                pk.x = __builtin_amdgcn_perm(c1.uv, c0.uv, 0x07060302u);
                pk.y = __builtin_amdgcn_perm(c3.uv, c2.uv, 0x07060302u);
                *reinterpret_cast<uint2*>(&Ps[pwt[j]]) = pk;
            }

            // O += P V; lsum via ones-MFMA on the same pf fragments
            // (wave-private Ps rows; lgkmcnt orders write->read)
            __builtin_amdgcn_s_setprio(1);
            #pragma unroll
            for (int ks = 0; ks < 2; ks++) {
                short8 pf = *reinterpret_cast<const short8*>(&Ps[prt[ks]]);
                accl = __builtin_amdgcn_mfma_f32_16x16x32_bf16(pf, ones8, accl, 0, 0, 0);
                #pragma unroll
                for (int j = 0; j < 4; j++) {
                    short8 vf = *reinterpret_cast<const short8*>(&Vt[hf][koff[j][ks]]);
                    acc[j] = __builtin_amdgcn_mfma_f32_16x16x32_bf16(pf, vf, acc[j], 0, 0, 0);
                }
            }
            __builtin_amdgcn_s_setprio(0);
        }

        // bottom barrier: all waves done reading Vt[kt]; drains K[kt+1] loads
        // (latency hidden under softmax+PV above). Vt halves free to restage.
        __syncthreads();
        if (kt < 15) {
            ISSUE_V(kbase + 128, 0);
            ISSUE_V(kbase + 192, 1);
        }
    }
#undef ISSUE_K
#undef ISSUE_V

    // epilogue: accl[r] (lane quad,l15) = sum_s P[q=quad*4+r][s] — the exact
    // row this lane writes. No cross-lane traffic at all.
    #pragma unroll
    for (int r = 0; r < 4; r++) {
        float iv = 1.0f / accl[r];
        int srow = qt * 64 + w * 16 + quad * 4 + r;
        #pragma unroll
        for (int j = 0; j < 4; j++)
            Ob[(b_ * 2048 + srow) * 1024 + h * 64 + j * 16 + l15] =
                f2bf(acc[j][r] * iv);
    }
}

// ---------------- Output GEMM, async-pipelined, XCD-swizzled -----------------
// v2: 128x64 tiles, grid 512 = 2 blocks/CU (was 256 = 1/CU: a barrier-per-
// iteration loop with no co-resident block leaves every vmcnt(0) drain fully
// exposed). A path and swizzles unchanged; B tile halved.
__global__ __launch_bounds__(256, 3) void gemm_out(
    const u16* __restrict__ Ob, const u16* __restrict__ Wto,
    const float* __restrict__ bo, float* __restrict__ out)
{
    __shared__ __align__(16) u16 As[2][128 * 32];
    __shared__ __align__(16) u16 Bs[2][64 * 32];
    int t = threadIdx.x;
    int w = t >> 6, lane = t & 63, l15 = lane & 15, quad = lane >> 4;
    int wm = (w >> 1) * 64, wn = (w & 1) * 32;
    int bid = blockIdx.x;
    int row0 = (bid & 31) * 128, col0 = (bid >> 5) * 64;

    int drow = lane >> 2;
    int gc8 = ((lane & 3) ^ (drow & 3) ^ ((drow >> 2) & 3)) * 8;
    int asw = ((quad ^ (l15 & 3) ^ ((l15 >> 2) & 3)) & 3) * 8;

    const u16* Ag = Ob + (row0 + drow) * 1024 + gc8;
    const u16* Bg = Wto + (col0 + drow) * 1024 + gc8;

    f32x4 acc[4][2];
    #pragma unroll
    for (int i = 0; i < 4; i++)
        #pragma unroll
        for (int j = 0; j < 2; j++)
            acc[i][j] = (f32x4){0.f, 0.f, 0.f, 0.f};

    #pragma unroll
    for (int q = 0; q < 2; q++) {
        int rr = w * 32 + q * 16;
        gld16(Ag + rr * 1024, &As[0][rr * 32]);
    }
    {
        int rr = w * 16;
        gld16(Bg + rr * 1024, &Bs[0][rr * 32]);
    }
    for (int kt = 0; kt < 32; kt++) {
        __syncthreads();
        int cur = kt & 1;
        if (kt < 31) {
            int k0 = (kt + 1) * 32;
            #pragma unroll
            for (int q = 0; q < 2; q++) {
                int rr = w * 32 + q * 16;
                gld16(Ag + rr * 1024 + k0, &As[cur ^ 1][rr * 32]);
            }
            int rr = w * 16;
            gld16(Bg + rr * 1024 + k0, &Bs[cur ^ 1][rr * 32]);
        }
        short8 a[4], b[2];
        #pragma unroll
        for (int i = 0; i < 4; i++)
            a[i] = *reinterpret_cast<const short8*>(&As[cur][(wm + i * 16 + l15) * 32 + asw]);
        #pragma unroll
        for (int j = 0; j < 2; j++)
            b[j] = *reinterpret_cast<const short8*>(&Bs[cur][(wn + j * 16 + l15) * 32 + asw]);
        #pragma unroll
        for (int i = 0; i < 4; i++)
            #pragma unroll
            for (int j = 0; j < 2; j++)
                acc[i][j] = __builtin_amdgcn_mfma_f32_16x16x32_bf16(a[i], b[j], acc[i][j], 0, 0, 0);
    }
    #pragma unroll
    for (int i = 0; i < 4; i++) {
        int rowb = row0 + wm + i * 16 + quad * 4;
        #pragma unroll
        for (int j = 0; j < 2; j++) {
            int col = col0 + wn + j * 16 + l15;
            float bb = bo[col];
            #pragma unroll
            for (int r = 0; r < 4; r++)
                out[(rowb + r) * 1024 + col] = acc[i][j][r] + bb;
        }
    }
}

extern "C" void kernel_launch(void* const* d_in, const int* in_sizes, int n_in,
                              void* d_out, int out_size, void* d_ws, size_t ws_size,
                              hipStream_t stream) {
    const float* X  = (const float*)d_in[0];
    const float* Wq = (const float*)d_in[1];
    const float* bq = (const float*)d_in[2];
    const float* Wk = (const float*)d_in[3];
    const float* bk = (const float*)d_in[4];
    const float* Wv = (const float*)d_in[5];
    const float* bv = (const float*)d_in[6];
    const float* Wo = (const float*)d_in[7];
    const float* bo = (const float*)d_in[8];
    float* out = (float*)d_out;

    char* ws = (char*)d_ws;
    u16* Xb    = (u16*)(ws);                      // 8 MB [4096,1024]; Ob aliases after use
    u16* Ob    = (u16*)(ws);                      // alias: Xb dead after gemm_qkv
    u16* Wqkv  = (u16*)(ws + (8u  << 20));        // 6 MB [3072,1024] (Wq pre-scaled)
    u16* Wto   = (u16*)(ws + (14u << 20));        // 2 MB [1024,1024]
    float* Bp  = (float*)(ws + (16u << 20));      // 12 KB packed bias (bq pre-scaled)
    u16* Qb    = (u16*)(ws + (17u << 20));        // 8 MB [B,H,S,Dk]
    u16* Kb    = (u16*)(ws + (25u << 20));        // 8 MB [B,H,S,Dk]
    u16* Vtg   = (u16*)(ws + (33u << 20));        // 8 MB [B,H,Dk,S]

    prep     <<<5121, 256, 0, stream>>>(X, Xb, Wq, Wk, Wv, Wo, bq, bk, bv, Wqkv, Wto, Bp);
    gemm_qkv <<<768, 256, 0, stream>>>(Xb, Wqkv, Bp, Qb, Kb, Vtg);
    attn     <<<1024, 256, 0, stream>>>(Qb, Kb, Vtg, Ob);
    gemm_out <<<512, 256, 0, stream>>>(Ob, Wto, bo, out);
}